// Round 6
// baseline (512.921 us; speedup 1.0000x reference)
//
#include <hip/hip_runtime.h>

// EncoderBlock on MI355X (gfx950). B=2,S=2048,D=1024,H=16,Dh=64.
// Round 6: software-pipelined K-loops (LDS double-buffer + fine-grained
// s_waitcnt vmcnt(4) + raw s_barrier, CK-style), FFN2 split-K x4 with bf16
// partials combined in final LN, single merged prep kernel.

#define DEV __device__ __forceinline__

typedef unsigned short u16;
typedef __attribute__((ext_vector_type(8))) short bfrag;    // 8 bf16 payload
typedef __attribute__((ext_vector_type(8))) __bf16 bf16x8;  // MFMA operand type
typedef __attribute__((ext_vector_type(4))) float facc;     // MFMA C/D frag

DEV float bf2f(u16 u) {
  unsigned int x = ((unsigned int)u) << 16;
  return __builtin_bit_cast(float, x);
}
DEV u16 f2bf(float f) {
  unsigned int x = __builtin_bit_cast(unsigned int, f);
  x += 0x7fffu + ((x >> 16) & 1u);  // RNE
  return (u16)(x >> 16);
}

DEV void gl2lds16(const u16* g, u16* l) {
  // async global->LDS DMA, 16B/lane; LDS dest = wave-uniform base + lane*16
  auto gp = (const __attribute__((address_space(1))) unsigned int*)(g);
  auto lp = (__attribute__((address_space(3))) unsigned int*)(l);
  __builtin_amdgcn_global_load_lds(gp, lp, 16, 0, 0);
}

DEV facc mfma16(bfrag a, bfrag b, facc c) {
  return __builtin_amdgcn_mfma_f32_16x16x32_bf16(
      __builtin_bit_cast(bf16x8, a), __builtin_bit_cast(bf16x8, b), c, 0, 0, 0);
}

// pipeline barriers (avoid compiler's vmcnt(0) drain before s_barrier)
DEV void bar_vm4() {   // previous tile's 4 DMA loads retired; newest 4 in flight
  asm volatile("s_waitcnt vmcnt(4)\ns_barrier" ::: "memory");
}
DEV void bar_lds() {   // my LDS reads done; no vm drain
  asm volatile("s_waitcnt lgkmcnt(0)\ns_barrier" ::: "memory");
}
DEV void bar_full() {  // full drain (prologue only)
  asm volatile("s_waitcnt vmcnt(0) lgkmcnt(0)\ns_barrier" ::: "memory");
}

// ---------------------------------------------------------------------------
// Merged prep: qkv transpose (jobs 0..3071), W1T (3072..7167),
// W2T (7168..11263), x cast (11264..15359). All fp32 -> bf16.
// ---------------------------------------------------------------------------
__global__ __launch_bounds__(256) void prep_kernel(
    const float* __restrict__ Wq, const float* __restrict__ Wk,
    const float* __restrict__ Wv, u16* __restrict__ WqkvT,
    const float* __restrict__ W1, u16* __restrict__ W1T,
    const float* __restrict__ W2, u16* __restrict__ W2T,
    const float* __restrict__ x, u16* __restrict__ xb) {
  __shared__ float tile[32][33];
  const int job = blockIdx.x;
  const int tr = threadIdx.x >> 5, tc = threadIdx.x & 31;

  if (job >= 11264) {  // cast x
    const int i = (job - 11264) * 1024 + threadIdx.x * 4;
    const float4 v = *(const float4*)(x + i);
    ushort4 o;
    o.x = f2bf(v.x); o.y = f2bf(v.y); o.z = f2bf(v.z); o.w = f2bf(v.w);
    *(ushort4*)(xb + i) = o;
    return;
  }

  const float* in;
  u16* out;
  int C, R, c0, r0;
  if (job < 3072) {  // qkv: [H][1024][64] -> rows which*1024+h*64+e, cols d
    const int z = job >> 6, rem = job & 63;
    const int which = z >> 4, h = z & 15;
    in = ((which == 0) ? Wq : (which == 1) ? Wk : Wv) + (size_t)h * 1024 * 64;
    out = WqkvT + ((size_t)which * 1024 + h * 64) * 1024;
    C = 64; R = 1024;
    c0 = (rem & 1) * 32; r0 = (rem >> 1) * 32;
  } else if (job < 7168) {  // W1 [1024][4096] -> W1T [4096][1024]
    const int rem = job - 3072;
    in = W1; out = W1T; C = 4096; R = 1024;
    c0 = (rem & 127) * 32; r0 = (rem >> 7) * 32;
  } else {  // W2 [4096][1024] -> W2T [1024][4096]
    const int rem = job - 7168;
    in = W2; out = W2T; C = 1024; R = 4096;
    c0 = (rem & 31) * 32; r0 = (rem >> 5) * 32;
  }
#pragma unroll
  for (int k = 0; k < 4; k++)
    tile[tr + 8 * k][tc] = in[(size_t)(r0 + tr + 8 * k) * C + c0 + tc];
  __syncthreads();
#pragma unroll
  for (int k = 0; k < 4; k++)
    out[(size_t)(c0 + tr + 8 * k) * R + r0 + tc] = f2bf(tile[tc][tr + 8 * k]);
}

// ---------------------------------------------------------------------------
// GEMM C[M][N] = A[M][K] * Bt[N][K]^T, 128x128 tile, BK=32, double-buffered
// pipelined K-loop. Each wave issues exactly 4 DMA loads per tile.
// MODE 0: QKV scatter +bias -> bf16 (V transposed [bh][e][s], packed stores).
// MODE 1: +bias, ReLU -> bf16.
// MODE 3: split-K partial -> bf16 partial buffer z (out0 + z*M*N).
// ---------------------------------------------------------------------------
template <int MODE>
__global__ __launch_bounds__(256) void gemm_bt(
    const u16* __restrict__ A, int lda, const u16* __restrict__ Bt, int ldb,
    int M, int N, int K,
    const float* __restrict__ bias0, const float* __restrict__ bias1,
    const float* __restrict__ bias2,
    void* __restrict__ out0, void* __restrict__ out1, void* __restrict__ out2) {
  __shared__ __align__(16) u16 As[2][4 * 128 * 8];  // 2 x 8 KB
  __shared__ __align__(16) u16 Bs[2][4 * 128 * 8];  // 2 x 8 KB
  const int tid = threadIdx.x;
  const int lane = tid & 63;
  const int wave = tid >> 6;
  const int laneM = lane & 15, quad = lane >> 4;
  const int m0 = blockIdx.y * 128, n0 = blockIdx.x * 128;
  const int wm = wave & 1, wn = wave >> 1;

  if (MODE == 3) {  // split-K: shift K-origin
    A += (size_t)blockIdx.z * K;
    Bt += (size_t)blockIdx.z * K;
  }

  // wave-uniform chunk bases for the two staging issues
  const int cA0 = wave * 64, cA1 = 256 + wave * 64;

  facc acc[4][4] = {};

  // prologue: tile 0 -> buf 0 (4 DMA issues per wave)
  {
    const int kc0 = cA0 >> 7, r0_ = cA0 & 127;
    const int kc1 = cA1 >> 7, r1_ = cA1 & 127;
    gl2lds16(A + (size_t)(m0 + r0_ + lane) * lda + kc0 * 8, As[0] + (size_t)cA0 * 8);
    gl2lds16(Bt + (size_t)(n0 + r0_ + lane) * ldb + kc0 * 8, Bs[0] + (size_t)cA0 * 8);
    gl2lds16(A + (size_t)(m0 + r1_ + lane) * lda + kc1 * 8, As[0] + (size_t)cA1 * 8);
    gl2lds16(Bt + (size_t)(n0 + r1_ + lane) * ldb + kc1 * 8, Bs[0] + (size_t)cA1 * 8);
  }

  int p = 0;
  for (int k0 = 0; k0 < K; k0 += 32) {
    // prefetch next tile into buf p^1 (wraps to 0 on last iter: harmless)
    int kn = k0 + 32;
    if (kn >= K) kn = 0;
    {
      const int q = p ^ 1;
      const int kc0 = cA0 >> 7, r0_ = cA0 & 127;
      const int kc1 = cA1 >> 7, r1_ = cA1 & 127;
      gl2lds16(A + (size_t)(m0 + r0_ + lane) * lda + (kn + kc0 * 8), As[q] + (size_t)cA0 * 8);
      gl2lds16(Bt + (size_t)(n0 + r0_ + lane) * ldb + (kn + kc0 * 8), Bs[q] + (size_t)cA0 * 8);
      gl2lds16(A + (size_t)(m0 + r1_ + lane) * lda + (kn + kc1 * 8), As[q] + (size_t)cA1 * 8);
      gl2lds16(Bt + (size_t)(n0 + r1_ + lane) * ldb + (kn + kc1 * 8), Bs[q] + (size_t)cA1 * 8);
    }
    bar_vm4();  // tile k0 resident in buf p; prefetch still in flight

    bfrag af[4], bfv[4];
#pragma unroll
    for (int i = 0; i < 4; i++)
      af[i] = *(const bfrag*)(As[p] + (quad * 128 + wm * 64 + i * 16 + laneM) * 8);
#pragma unroll
    for (int j = 0; j < 4; j++)
      bfv[j] = *(const bfrag*)(Bs[p] + (quad * 128 + wn * 64 + j * 16 + laneM) * 8);
#pragma unroll
    for (int i = 0; i < 4; i++)
#pragma unroll
      for (int j = 0; j < 4; j++)
        acc[i][j] = mfma16(af[i], bfv[j], acc[i][j]);

    bar_lds();  // readers of buf p done before it is re-targeted
    p ^= 1;
  }

  // epilogue: C/D layout col=lane&15, row=quad*4+v
#pragma unroll
  for (int i = 0; i < 4; i++) {
#pragma unroll
    for (int j = 0; j < 4; j++) {
      const int col = n0 + wn * 64 + j * 16 + laneM;
      const int row0 = m0 + wm * 64 + i * 16 + quad * 4;
      if (MODE == 0) {
        const int which = col >> 10, c = col & 1023;
        const float* bp = (which == 0) ? bias0 : (which == 1) ? bias1 : bias2;
        u16* op = (u16*)((which == 0) ? out0 : (which == 1) ? out1 : out2);
        const float bb = bp[c];
        const int b = row0 >> 11, s0 = row0 & 2047;
        const int h = c >> 6, e = c & 63;
        if (which == 2) {  // V^T [bh][e][s]: 4 consecutive s -> one 8B store
          ushort4 pk;
          pk.x = f2bf(acc[i][j][0] + bb);
          pk.y = f2bf(acc[i][j][1] + bb);
          pk.z = f2bf(acc[i][j][2] + bb);
          pk.w = f2bf(acc[i][j][3] + bb);
          *(ushort4*)(op + ((size_t)((b * 16 + h) * 64 + e)) * 2048 + s0) = pk;
        } else {
#pragma unroll
          for (int v = 0; v < 4; v++)
            op[((size_t)(b * 16 + h) * 2048 + s0 + v) * 64 + e] =
                f2bf(acc[i][j][v] + bb);
        }
      } else if (MODE == 1) {
        const float bb = bias0[col];
#pragma unroll
        for (int v = 0; v < 4; v++)
          ((u16*)out0)[(size_t)(row0 + v) * N + col] =
              f2bf(fmaxf(acc[i][j][v] + bb, 0.0f));
      } else {  // MODE 3: bf16 partial z
        u16* op = (u16*)out0 + (size_t)blockIdx.z * M * N;
#pragma unroll
        for (int v = 0; v < 4; v++)
          op[(size_t)(row0 + v) * N + col] = f2bf(acc[i][j][v]);
      }
    }
  }
}

// ---------------------------------------------------------------------------
// Flash attention, pipelined: per (b,h), Q-tile=64 (16 rows/wave), K-tile=64.
// p = 2^(qk*0.125*log2e + maskbias), no online max (scores bounded).
// Q,K bf16 [bh][s][64]; V bf16 TRANSPOSED [bh][e][s]. Out fp32.
// K and V tiles double-buffered via DMA (4 issues/wave/tile).
// ---------------------------------------------------------------------------
__global__ __launch_bounds__(256) void attn_kernel(
    const u16* __restrict__ Qb, const u16* __restrict__ Kb,
    const u16* __restrict__ VTg, const int* __restrict__ mask,
    float* __restrict__ attn_out) {
  __shared__ __align__(16) u16 KS[2][8 * 64 * 8];  // 2 x 8 KB (Q stage first)
  __shared__ __align__(16) u16 VS[2][8 * 64 * 8];  // 2 x 8 KB, chunk kc*64+e
  __shared__ __align__(16) u16 PS[64 * 72];        // P (XOR-swizzled cols)
  __shared__ float MB[2048];                       // additive mask bias
  const int tid = threadIdx.x;
  const int lane = tid & 63;
  const int wave = tid >> 6;
  const int laneM = lane & 15, quad = lane >> 4;
  const int bh = blockIdx.y, b = bh >> 4, h = bh & 15;
  const int q0 = blockIdx.x * 64;
  const u16* Qh = Qb + (size_t)bh * 2048 * 64;
  const u16* Kh = Kb + (size_t)bh * 2048 * 64;
  const u16* Vh = VTg + (size_t)bh * 64 * 2048;
  const float SC = 0.125f * 1.4426950408889634f;  // Dh^-0.5 * log2(e)

  // mask -> additive bias table (once per block)
#pragma unroll
  for (int t = 0; t < 8; t++) {
    const int i = t * 256 + tid;
    MB[i] = mask[b * 2048 + i] ? 0.0f : -1e30f;
  }

  // stage Q tile (64x64) into KS[0], full drain, read qf, release KS[0]
  {
    const int c0 = wave * 64, c1 = 256 + wave * 64;
    gl2lds16(Qh + (size_t)(q0 + lane) * 64 + (c0 >> 6) * 8, KS[0] + (size_t)c0 * 8);
    gl2lds16(Qh + (size_t)(q0 + lane) * 64 + (c1 >> 6) * 8, KS[0] + (size_t)c1 * 8);
  }
  bar_full();  // Q resident + MB table visible
  bfrag qf[2];
#pragma unroll
  for (int hf = 0; hf < 2; hf++)
    qf[hf] = *(const bfrag*)(KS[0] + ((hf * 4 + quad) * 64 + wave * 16 + laneM) * 8);
  bar_lds();  // everyone has qf; KS[0] can be overwritten

  // prologue: tile t0=0 -> buf 0 (K: 2 issues, V: 2 issues per wave)
  {
    const int c0 = wave * 64, c1 = 256 + wave * 64;
    gl2lds16(Kh + (size_t)lane * 64 + (c0 >> 6) * 8, KS[0] + (size_t)c0 * 8);
    gl2lds16(Kh + (size_t)lane * 64 + (c1 >> 6) * 8, KS[0] + (size_t)c1 * 8);
    gl2lds16(Vh + (size_t)lane * 2048 + (c0 >> 6) * 8, VS[0] + (size_t)c0 * 8);
    gl2lds16(Vh + (size_t)lane * 2048 + (c1 >> 6) * 8, VS[0] + (size_t)c1 * 8);
  }

  float lsum[4] = {0.0f, 0.0f, 0.0f, 0.0f};
  facc oacc[4] = {};
  const int pq = quad ^ ((laneM >> 2) & 2);  // PS read swizzle

  int p = 0;
  for (int t0 = 0; t0 < 2048; t0 += 64) {
    // prefetch next K/V tile (wraps on last iter: harmless)
    const int tn = (t0 + 64) & 2047;
    {
      const int q = p ^ 1;
      const int c0 = wave * 64, c1 = 256 + wave * 64;
      gl2lds16(Kh + (size_t)(tn + lane) * 64 + (c0 >> 6) * 8, KS[q] + (size_t)c0 * 8);
      gl2lds16(Kh + (size_t)(tn + lane) * 64 + (c1 >> 6) * 8, KS[q] + (size_t)c1 * 8);
      gl2lds16(Vh + (size_t)lane * 2048 + tn + (c0 >> 6) * 8, VS[q] + (size_t)c0 * 8);
      gl2lds16(Vh + (size_t)lane * 2048 + tn + (c1 >> 6) * 8, VS[q] + (size_t)c1 * 8);
    }
    bar_vm4();  // tile t0 resident in buf p

    // S = Q K^T
    facc sacc[4] = {};
#pragma unroll
    for (int j8 = 0; j8 < 4; j8++)
#pragma unroll
      for (int hf = 0; hf < 2; hf++) {
        bfrag kf = *(const bfrag*)(KS[p] + ((hf * 4 + quad) * 64 + j8 * 16 + laneM) * 8);
        sacc[j8] = mfma16(qf[hf], kf, sacc[j8]);
      }

    float mb4[4];
#pragma unroll
    for (int j8 = 0; j8 < 4; j8++) mb4[j8] = MB[t0 + j8 * 16 + laneM];

    // p = 2^(s*SC + bias); per-lane partial sums; write bf16 P (swizzled)
#pragma unroll
    for (int v = 0; v < 4; v++) {
      u16* psrow = PS + (wave * 16 + quad * 4 + v) * 72 + laneM;
#pragma unroll
      for (int j8 = 0; j8 < 4; j8++) {
        const float pv = exp2f(fmaf(sacc[j8][v], SC, mb4[j8]));
        lsum[v] += pv;
        psrow[(j8 ^ (quad >> 1)) * 16] =
            (u16)((__builtin_bit_cast(unsigned int, pv) + 0x8000u) >> 16);
      }
    }

    // O += P @ V  (PS rows wave-private; VS chunk = kc*64 + e)
#pragma unroll
    for (int kc4 = 0; kc4 < 2; kc4++) {
      bfrag pf = *(const bfrag*)(PS + (wave * 16 + laneM) * 72 + kc4 * 32 + pq * 8);
#pragma unroll
      for (int je = 0; je < 4; je++) {
        bfrag vf = *(const bfrag*)(VS[p] + ((kc4 * 4 + quad) * 64 + je * 16 + laneM) * 8);
        oacc[je] = mfma16(pf, vf, oacc[je]);
      }
    }

    bar_lds();  // readers of buf p done before it is re-targeted
    p ^= 1;
  }

  // final row-sum reduce (16-lane groups share a row) and scatter
#pragma unroll
  for (int v = 0; v < 4; v++) {
    float l = lsum[v];
    l += __shfl_xor(l, 1, 16);
    l += __shfl_xor(l, 2, 16);
    l += __shfl_xor(l, 4, 16);
    l += __shfl_xor(l, 8, 16);
    const float inv = 1.0f / l;
    const int s = q0 + wave * 16 + quad * 4 + v;
    float* dst = attn_out + ((size_t)(b * 2048 + s)) * 1024 + h * 64;
#pragma unroll
    for (int je = 0; je < 4; je++)
      dst[je * 16 + laneM] = oacc[je][v] * inv;
  }
}

// ---------------------------------------------------------------------------
// out = base + alpha*(y-mean)/(std+eps) + beta, D=1024, fp32 in/out.
// ---------------------------------------------------------------------------
__global__ __launch_bounds__(256) void ln_res(
    const float* __restrict__ base, const float* __restrict__ y,
    const float* __restrict__ alpha, const float* __restrict__ beta,
    float* __restrict__ outf, u16* __restrict__ outb) {
  __shared__ float red[4];
  const int row = blockIdx.x;
  const int t = threadIdx.x;
  const size_t off = (size_t)row * 1024 + t * 4;

  const float4 yv = *(const float4*)(y + off);

  float s = yv.x + yv.y + yv.z + yv.w;
#pragma unroll
  for (int o = 1; o < 64; o <<= 1) s += __shfl_xor(s, o, 64);
  if ((t & 63) == 0) red[t >> 6] = s;
  __syncthreads();
  const float mean = (red[0] + red[1] + red[2] + red[3]) * (1.0f / 1024.0f);
  __syncthreads();

  const float d0 = yv.x - mean, d1 = yv.y - mean, d2 = yv.z - mean, d3 = yv.w - mean;
  float ss = d0 * d0 + d1 * d1 + d2 * d2 + d3 * d3;
#pragma unroll
  for (int o = 1; o < 64; o <<= 1) ss += __shfl_xor(ss, o, 64);
  if ((t & 63) == 0) red[t >> 6] = ss;
  __syncthreads();
  const float var = (red[0] + red[1] + red[2] + red[3]) * (1.0f / 1023.0f);
  const float rstd = 1.0f / (sqrtf(var) + 1e-6f);

  const float4 bv = *(const float4*)(base + off);
  const float4 av = *(const float4*)(alpha + (size_t)t * 4);
  const float4 ev = *(const float4*)(beta + (size_t)t * 4);

  float4 ov;
  ov.x = bv.x + av.x * d0 * rstd + ev.x;
  ov.y = bv.y + av.y * d1 * rstd + ev.y;
  ov.z = bv.z + av.z * d2 * rstd + ev.z;
  ov.w = bv.w + av.w * d3 * rstd + ev.w;
  *(float4*)(outf + off) = ov;
  ushort4 ob;
  ob.x = f2bf(ov.x); ob.y = f2bf(ov.y); ob.z = f2bf(ov.z); ob.w = f2bf(ov.w);
  *(ushort4*)(outb + off) = ob;
}

// Final LN: y = sum of 4 bf16 split-K partials + bias; out fp32.
__global__ __launch_bounds__(256) void ln_res4(
    const float* __restrict__ base, const u16* __restrict__ parts,
    const float* __restrict__ biasv,
    const float* __restrict__ alpha, const float* __restrict__ beta,
    float* __restrict__ outf) {
  __shared__ float red[4];
  const int row = blockIdx.x;
  const int t = threadIdx.x;
  const size_t off = (size_t)row * 1024 + t * 4;
  const size_t stride = (size_t)4096 * 1024;

  float4 yv = *(const float4*)(biasv + (size_t)t * 4);
#pragma unroll
  for (int z = 0; z < 4; z++) {
    const ushort4 pz = *(const ushort4*)(parts + z * stride + off);
    yv.x += bf2f(pz.x); yv.y += bf2f(pz.y);
    yv.z += bf2f(pz.z); yv.w += bf2f(pz.w);
  }

  float s = yv.x + yv.y + yv.z + yv.w;
#pragma unroll
  for (int o = 1; o < 64; o <<= 1) s += __shfl_xor(s, o, 64);
  if ((t & 63) == 0) red[t >> 6] = s;
  __syncthreads();
  const float mean = (red[0] + red[1] + red[2] + red[3]) * (1.0f / 1024.0f);
  __syncthreads();

  const float d0 = yv.x - mean, d1 = yv.y - mean, d2 = yv.z - mean, d3 = yv.w - mean;
  float ss = d0 * d0 + d1 * d1 + d2 * d2 + d3 * d3;
#pragma unroll
  for (int o = 1; o < 64; o <<= 1) ss += __shfl_xor(ss, o, 64);
  if ((t & 63) == 0) red[t >> 6] = ss;
  __syncthreads();
  const float var = (red[0] + red[1] + red[2] + red[3]) * (1.0f / 1023.0f);
  const float rstd = 1.0f / (sqrtf(var) + 1e-6f);

  const float4 bv = *(const float4*)(base + off);
  const float4 av = *(const float4*)(alpha + (size_t)t * 4);
  const float4 ev = *(const float4*)(beta + (size_t)t * 4);

  float4 ov;
  ov.x = bv.x + av.x * d0 * rstd + ev.x;
  ov.y = bv.y + av.y * d1 * rstd + ev.y;
  ov.z = bv.z + av.z * d2 * rstd + ev.z;
  ov.w = bv.w + av.w * d3 * rstd + ev.w;
  *(float4*)(outf + off) = ov;
}

// ---------------------------------------------------------------------------
extern "C" void kernel_launch(void* const* d_in, const int* in_sizes, int n_in,
                              void* d_out, int out_size, void* d_ws,
                              size_t ws_size, hipStream_t stream) {
  const float* x  = (const float*)d_in[0];
  const int* mask = (const int*)d_in[1];
  const float* Wq = (const float*)d_in[2];
  const float* bq = (const float*)d_in[3];
  const float* Wk = (const float*)d_in[4];
  const float* bk = (const float*)d_in[5];
  const float* Wv = (const float*)d_in[6];
  const float* bv = (const float*)d_in[7];
  const float* W1 = (const float*)d_in[8];
  const float* b1 = (const float*)d_in[9];
  const float* W2 = (const float*)d_in[10];
  const float* b2 = (const float*)d_in[11];
  const float* alpha1 = (const float*)d_in[12];
  const float* beta1  = (const float*)d_in[13];
  const float* alpha2 = (const float*)d_in[14];
  const float* beta2  = (const float*)d_in[15];
  float* out = (float*)d_out;

  // workspace carve-up (bytes), total ~158 MB
  char* p = (char*)d_ws;
  u16* xb      = (u16*)p;  p += (size_t)4096 * 1024 * 2;
  u16* WqkvT   = (u16*)p;  p += (size_t)3072 * 1024 * 2;
  u16* W1T     = (u16*)p;  p += (size_t)4096 * 1024 * 2;
  u16* W2T     = (u16*)p;  p += (size_t)1024 * 4096 * 2;
  u16* Qbuf    = (u16*)p;  p += (size_t)32 * 2048 * 64 * 2;
  u16* Kbuf    = (u16*)p;  p += (size_t)32 * 2048 * 64 * 2;
  u16* Vbuf    = (u16*)p;  p += (size_t)32 * 2048 * 64 * 2;  // V^T [bh][e][s]
  float* attn  = (float*)p; p += (size_t)4096 * 1024 * 4;
  float* x1f   = (float*)p; p += (size_t)4096 * 1024 * 4;
  u16* x1b     = (u16*)p;  p += (size_t)4096 * 1024 * 2;
  u16* hbuf    = (u16*)p;  p += (size_t)4096 * 4096 * 2;
  u16* ffnp    = (u16*)p;  p += (size_t)4 * 4096 * 1024 * 2;  // 4 bf16 partials

  // 1) merged prep: transposes + x cast
  prep_kernel<<<15360, 256, 0, stream>>>(Wq, Wk, Wv, WqkvT, W1, W1T, W2, W2T,
                                         x, xb);

  // 2) fused QKV projection (V written transposed)
  gemm_bt<0><<<dim3(24, 32), 256, 0, stream>>>(
      xb, 1024, WqkvT, 1024, 4096, 3072, 1024, bq, bk, bv, Qbuf, Kbuf, Vbuf);

  // 3) flash attention -> fp32 attn
  attn_kernel<<<dim3(32, 32), 256, 0, stream>>>(Qbuf, Kbuf, Vbuf, mask, attn);

  // 4) x1 = x + LN(attn)   (fp32 + bf16 copies)
  ln_res<<<4096, 256, 0, stream>>>(x, attn, alpha1, beta1, x1f, x1b);

  // 5) h = relu(x1 @ W1 + b1) -> bf16
  gemm_bt<1><<<dim3(32, 32), 256, 0, stream>>>(
      x1b, 1024, W1T, 1024, 4096, 4096, 1024, b1, nullptr, nullptr,
      hbuf, nullptr, nullptr);

  // 6) ffn partials: h @ W2 split-K x4 -> bf16 partials
  gemm_bt<3><<<dim3(8, 32, 4), 256, 0, stream>>>(
      hbuf, 4096, W2T, 4096, 4096, 1024, 1024, nullptr, nullptr, nullptr,
      ffnp, nullptr, nullptr);

  // 7) out = x1 + LN(p0+p1+p2+p3 + b2)
  ln_res4<<<4096, 256, 0, stream>>>(x1f, ffnp, b2, alpha2, beta2, out);
}

// Round 7
// 481.284 us; speedup vs baseline: 1.0657x; 1.0657x over previous
//
#include <hip/hip_runtime.h>

// EncoderBlock on MI355X (gfx950). B=2,S=2048,D=1024,H=16,Dh=64.
// Round 7: revert to single-buffer K-loops (round-5 structure; round-6 dbuf
// regressed via LDS-occupancy). Attention split-S x2 (grid 2048 blocks,
// linear partial combine fused into LN). FFN2 split-K x4 (bf16 partials).

#define DEV __device__ __forceinline__

typedef unsigned short u16;
typedef __attribute__((ext_vector_type(8))) short bfrag;    // 8 bf16 payload
typedef __attribute__((ext_vector_type(8))) __bf16 bf16x8;  // MFMA operand type
typedef __attribute__((ext_vector_type(4))) float facc;     // MFMA C/D frag

DEV float bf2f(u16 u) {
  unsigned int x = ((unsigned int)u) << 16;
  return __builtin_bit_cast(float, x);
}
DEV u16 f2bf(float f) {
  unsigned int x = __builtin_bit_cast(unsigned int, f);
  x += 0x7fffu + ((x >> 16) & 1u);  // RNE
  return (u16)(x >> 16);
}

DEV void gl2lds16(const u16* g, u16* l) {
  // async global->LDS DMA, 16B/lane; LDS dest = wave-uniform base + lane*16
  auto gp = (const __attribute__((address_space(1))) unsigned int*)(g);
  auto lp = (__attribute__((address_space(3))) unsigned int*)(l);
  __builtin_amdgcn_global_load_lds(gp, lp, 16, 0, 0);
}

DEV facc mfma16(bfrag a, bfrag b, facc c) {
  return __builtin_amdgcn_mfma_f32_16x16x32_bf16(
      __builtin_bit_cast(bf16x8, a), __builtin_bit_cast(bf16x8, b), c, 0, 0, 0);
}

// ---------------------------------------------------------------------------
// Merged prep: qkv transpose (jobs 0..3071), W1T (3072..7167),
// W2T (7168..11263), x cast (11264..15359). All fp32 -> bf16.
// ---------------------------------------------------------------------------
__global__ __launch_bounds__(256) void prep_kernel(
    const float* __restrict__ Wq, const float* __restrict__ Wk,
    const float* __restrict__ Wv, u16* __restrict__ WqkvT,
    const float* __restrict__ W1, u16* __restrict__ W1T,
    const float* __restrict__ W2, u16* __restrict__ W2T,
    const float* __restrict__ x, u16* __restrict__ xb) {
  __shared__ float tile[32][33];
  const int job = blockIdx.x;
  const int tr = threadIdx.x >> 5, tc = threadIdx.x & 31;

  if (job >= 11264) {  // cast x
    const int i = (job - 11264) * 1024 + threadIdx.x * 4;
    const float4 v = *(const float4*)(x + i);
    ushort4 o;
    o.x = f2bf(v.x); o.y = f2bf(v.y); o.z = f2bf(v.z); o.w = f2bf(v.w);
    *(ushort4*)(xb + i) = o;
    return;
  }

  const float* in;
  u16* out;
  int C, R, c0, r0;
  if (job < 3072) {  // qkv: [H][1024][64] -> rows which*1024+h*64+e, cols d
    const int z = job >> 6, rem = job & 63;
    const int which = z >> 4, h = z & 15;
    in = ((which == 0) ? Wq : (which == 1) ? Wk : Wv) + (size_t)h * 1024 * 64;
    out = WqkvT + ((size_t)which * 1024 + h * 64) * 1024;
    C = 64; R = 1024;
    c0 = (rem & 1) * 32; r0 = (rem >> 1) * 32;
  } else if (job < 7168) {  // W1 [1024][4096] -> W1T [4096][1024]
    const int rem = job - 3072;
    in = W1; out = W1T; C = 4096; R = 1024;
    c0 = (rem & 127) * 32; r0 = (rem >> 7) * 32;
  } else {  // W2 [4096][1024] -> W2T [1024][4096]
    const int rem = job - 7168;
    in = W2; out = W2T; C = 1024; R = 4096;
    c0 = (rem & 31) * 32; r0 = (rem >> 5) * 32;
  }
#pragma unroll
  for (int k = 0; k < 4; k++)
    tile[tr + 8 * k][tc] = in[(size_t)(r0 + tr + 8 * k) * C + c0 + tc];
  __syncthreads();
#pragma unroll
  for (int k = 0; k < 4; k++)
    out[(size_t)(c0 + tr + 8 * k) * R + r0 + tc] = f2bf(tile[tc][tr + 8 * k]);
}

// ---------------------------------------------------------------------------
// GEMM C[M][N] = A[M][K] * Bt[N][K]^T, 128x128 tile, BK=32, single-buffer
// m97 structure (2 barriers/tile, DMA staging).
// MODE 0: QKV scatter +bias -> bf16 (V transposed [bh][e][s], packed stores).
// MODE 1: +bias, ReLU -> bf16.
// MODE 3: split-K partial -> bf16 partial buffer z (out0 + z*M*N).
// ---------------------------------------------------------------------------
template <int MODE>
__global__ __launch_bounds__(256) void gemm_bt(
    const u16* __restrict__ A, int lda, const u16* __restrict__ Bt, int ldb,
    int M, int N, int K,
    const float* __restrict__ bias0, const float* __restrict__ bias1,
    const float* __restrict__ bias2,
    void* __restrict__ out0, void* __restrict__ out1, void* __restrict__ out2) {
  __shared__ __align__(16) u16 As[4 * 128 * 8];  // 8 KB
  __shared__ __align__(16) u16 Bs[4 * 128 * 8];  // 8 KB
  const int tid = threadIdx.x;
  const int lane = tid & 63;
  const int wave = tid >> 6;
  const int laneM = lane & 15, quad = lane >> 4;
  const int m0 = blockIdx.y * 128, n0 = blockIdx.x * 128;
  const int wm = wave & 1, wn = wave >> 1;

  if (MODE == 3) {  // split-K: shift K-origin
    A += (size_t)blockIdx.z * K;
    Bt += (size_t)blockIdx.z * K;
  }

  facc acc[4][4] = {};

  for (int k0 = 0; k0 < K; k0 += 32) {
    __syncthreads();  // previous tile's readers done
#pragma unroll
    for (int t = 0; t < 2; t++) {
      const int c0 = t * 256 + wave * 64;  // wave-uniform chunk base
      const int kc = c0 >> 7, r0 = c0 & 127;
      gl2lds16(A + (size_t)(m0 + r0 + lane) * lda + (k0 + kc * 8),
               As + (size_t)c0 * 8);
      gl2lds16(Bt + (size_t)(n0 + r0 + lane) * ldb + (k0 + kc * 8),
               Bs + (size_t)c0 * 8);
    }
    __syncthreads();  // staging visible

    bfrag af[4], bfv[4];
#pragma unroll
    for (int i = 0; i < 4; i++)
      af[i] = *(const bfrag*)(As + (quad * 128 + wm * 64 + i * 16 + laneM) * 8);
#pragma unroll
    for (int j = 0; j < 4; j++)
      bfv[j] = *(const bfrag*)(Bs + (quad * 128 + wn * 64 + j * 16 + laneM) * 8);
#pragma unroll
    for (int i = 0; i < 4; i++)
#pragma unroll
      for (int j = 0; j < 4; j++)
        acc[i][j] = mfma16(af[i], bfv[j], acc[i][j]);
  }

  // epilogue: C/D layout col=lane&15, row=quad*4+v
#pragma unroll
  for (int i = 0; i < 4; i++) {
#pragma unroll
    for (int j = 0; j < 4; j++) {
      const int col = n0 + wn * 64 + j * 16 + laneM;
      const int row0 = m0 + wm * 64 + i * 16 + quad * 4;
      if (MODE == 0) {
        const int which = col >> 10, c = col & 1023;
        const float* bp = (which == 0) ? bias0 : (which == 1) ? bias1 : bias2;
        u16* op = (u16*)((which == 0) ? out0 : (which == 1) ? out1 : out2);
        const float bb = bp[c];
        const int b = row0 >> 11, s0 = row0 & 2047;
        const int h = c >> 6, e = c & 63;
        if (which == 2) {  // V^T [bh][e][s]: 4 consecutive s -> one 8B store
          ushort4 pk;
          pk.x = f2bf(acc[i][j][0] + bb);
          pk.y = f2bf(acc[i][j][1] + bb);
          pk.z = f2bf(acc[i][j][2] + bb);
          pk.w = f2bf(acc[i][j][3] + bb);
          *(ushort4*)(op + ((size_t)((b * 16 + h) * 64 + e)) * 2048 + s0) = pk;
        } else {
#pragma unroll
          for (int v = 0; v < 4; v++)
            op[((size_t)(b * 16 + h) * 2048 + s0 + v) * 64 + e] =
                f2bf(acc[i][j][v] + bb);
        }
      } else if (MODE == 1) {
        const float bb = bias0[col];
#pragma unroll
        for (int v = 0; v < 4; v++)
          ((u16*)out0)[(size_t)(row0 + v) * N + col] =
              f2bf(fmaxf(acc[i][j][v] + bb, 0.0f));
      } else {  // MODE 3: bf16 partial z
        u16* op = (u16*)out0 + (size_t)blockIdx.z * M * N;
#pragma unroll
        for (int v = 0; v < 4; v++)
          op[(size_t)(row0 + v) * N + col] = f2bf(acc[i][j][v]);
      }
    }
  }
}

// ---------------------------------------------------------------------------
// Flash attention, split-S: block handles Q-tile=64 (16 rows/wave) and HALF
// the key range (z = blockIdx.z). Fixed-max softmax (scores bounded):
// p = 2^(qk*0.125*log2e + maskbias). Partials are linear: writes
// unnormalized O-half and l-half; LN kernel combines.
// Q,K bf16 [bh][s][64]; V bf16 TRANSPOSED [bh][e][s].
// ---------------------------------------------------------------------------
__global__ __launch_bounds__(256) void attn_kernel(
    const u16* __restrict__ Qb, const u16* __restrict__ Kb,
    const u16* __restrict__ VTg, const int* __restrict__ mask,
    float* __restrict__ Opart, float* __restrict__ lbuf) {
  __shared__ __align__(16) u16 KS[8 * 64 * 8];  // 8 KB: Q stage, then K tiles
  __shared__ __align__(16) u16 VS[8 * 64 * 8];  // 8 KB: V^T chunks kc*64+e
  __shared__ __align__(16) u16 PS[64 * 72];     // P (XOR-swizzled cols)
  __shared__ float MB[1024];                    // additive mask bias (half)
  const int tid = threadIdx.x;
  const int lane = tid & 63;
  const int wave = tid >> 6;
  const int laneM = lane & 15, quad = lane >> 4;
  const int bh = blockIdx.y, b = bh >> 4, h = bh & 15;
  const int q0 = blockIdx.x * 64;
  const int z = blockIdx.z;
  const int sbase = z * 1024;
  const u16* Qh = Qb + (size_t)bh * 2048 * 64;
  const u16* Kh = Kb + (size_t)bh * 2048 * 64 + (size_t)sbase * 64;
  const u16* Vh = VTg + (size_t)bh * 64 * 2048 + sbase;
  const float SC = 0.125f * 1.4426950408889634f;  // Dh^-0.5 * log2(e)

  // mask -> additive bias table for this half (once per block)
#pragma unroll
  for (int t = 0; t < 4; t++) {
    const int i = t * 256 + tid;
    MB[i] = mask[b * 2048 + sbase + i] ? 0.0f : -1e30f;
  }

  // stage Q tile (64x64) into KS as chunks c = kc*64 + r
#pragma unroll
  for (int t = 0; t < 2; t++) {
    const int c0 = t * 256 + wave * 64;
    gl2lds16(Qh + (size_t)(q0 + lane) * 64 + (c0 >> 6) * 8, KS + (size_t)c0 * 8);
  }
  __syncthreads();
  bfrag qf[2];
#pragma unroll
  for (int hf = 0; hf < 2; hf++)
    qf[hf] = *(const bfrag*)(KS + ((hf * 4 + quad) * 64 + wave * 16 + laneM) * 8);

  float lsum[4] = {0.0f, 0.0f, 0.0f, 0.0f};
  facc oacc[4] = {};
  const int pq = quad ^ ((laneM >> 2) & 2);  // PS read swizzle

  for (int t0 = 0; t0 < 1024; t0 += 64) {
    __syncthreads();  // all waves done reading KS/VS (qf on iter 0)
    // stage K tile (64x64), chunks c = kc*64 + r
#pragma unroll
    for (int t = 0; t < 2; t++) {
      const int c0 = t * 256 + wave * 64;
      gl2lds16(Kh + (size_t)(t0 + lane) * 64 + (c0 >> 6) * 8, KS + (size_t)c0 * 8);
    }
    // stage V^T tile, chunks c = kc*64 + e
#pragma unroll
    for (int t = 0; t < 2; t++) {
      const int c0 = t * 256 + wave * 64;
      gl2lds16(Vh + (size_t)lane * 2048 + t0 + (c0 >> 6) * 8, VS + (size_t)c0 * 8);
    }
    __syncthreads();

    // S = Q K^T
    facc sacc[4] = {};
#pragma unroll
    for (int j8 = 0; j8 < 4; j8++)
#pragma unroll
      for (int hf = 0; hf < 2; hf++) {
        bfrag kf = *(const bfrag*)(KS + ((hf * 4 + quad) * 64 + j8 * 16 + laneM) * 8);
        sacc[j8] = mfma16(qf[hf], kf, sacc[j8]);
      }

    float mb4[4];
#pragma unroll
    for (int j8 = 0; j8 < 4; j8++) mb4[j8] = MB[t0 + j8 * 16 + laneM];

    // p = 2^(s*SC + bias); per-lane partial sums; write bf16 P (swizzled)
#pragma unroll
    for (int v = 0; v < 4; v++) {
      u16* psrow = PS + (wave * 16 + quad * 4 + v) * 72 + laneM;
#pragma unroll
      for (int j8 = 0; j8 < 4; j8++) {
        const float pv = exp2f(fmaf(sacc[j8][v], SC, mb4[j8]));
        lsum[v] += pv;
        psrow[(j8 ^ (quad >> 1)) * 16] =
            (u16)((__builtin_bit_cast(unsigned int, pv) + 0x8000u) >> 16);
      }
    }

    // O += P @ V  (PS rows wave-private; VS chunk = kc*64 + e)
#pragma unroll
    for (int kc4 = 0; kc4 < 2; kc4++) {
      bfrag pf = *(const bfrag*)(PS + (wave * 16 + laneM) * 72 + kc4 * 32 + pq * 8);
#pragma unroll
      for (int je = 0; je < 4; je++) {
        bfrag vf = *(const bfrag*)(VS + ((kc4 * 4 + quad) * 64 + je * 16 + laneM) * 8);
        oacc[je] = mfma16(pf, vf, oacc[je]);
      }
    }
  }

  // reduce l over the 16-lane row group; write unnormalized partials
#pragma unroll
  for (int v = 0; v < 4; v++) {
    float l = lsum[v];
    l += __shfl_xor(l, 1, 16);
    l += __shfl_xor(l, 2, 16);
    l += __shfl_xor(l, 4, 16);
    l += __shfl_xor(l, 8, 16);
    const int s = q0 + wave * 16 + quad * 4 + v;
    if (laneM == 0) lbuf[((size_t)(z * 32 + bh)) * 2048 + s] = l;
    float* dst = Opart + (size_t)z * 4096 * 1024 +
                 ((size_t)(b * 2048 + s)) * 1024 + h * 64;
#pragma unroll
    for (int je = 0; je < 4; je++)
      dst[je * 16 + laneM] = oacc[je][v];
  }
}

// ---------------------------------------------------------------------------
// x1 = x + LN((O0+O1)/(l0+l1)); fused attention combine + LayerNorm.
// Writes fp32 + bf16 copies. torch-style: ddof=1 var, divide by (std+eps).
// ---------------------------------------------------------------------------
__global__ __launch_bounds__(256) void ln_attn(
    const float* __restrict__ base, const float* __restrict__ Opart,
    const float* __restrict__ lbuf,
    const float* __restrict__ alpha, const float* __restrict__ beta,
    float* __restrict__ outf, u16* __restrict__ outb) {
  __shared__ float red[4];
  const int row = blockIdx.x;           // token = b*2048 + s
  const int t = threadIdx.x;
  const int b = row >> 11, s = row & 2047;
  const int h = t >> 4;                 // head of columns t*4..t*4+3
  const size_t off = (size_t)row * 1024 + t * 4;
  const size_t zstride = (size_t)4096 * 1024;

  const float l0 = lbuf[((size_t)(b * 16 + h)) * 2048 + s];
  const float l1 = lbuf[((size_t)(32 + b * 16 + h)) * 2048 + s];
  const float inv = 1.0f / (l0 + l1);

  const float4 o0 = *(const float4*)(Opart + off);
  const float4 o1 = *(const float4*)(Opart + zstride + off);
  float4 yv;
  yv.x = (o0.x + o1.x) * inv;
  yv.y = (o0.y + o1.y) * inv;
  yv.z = (o0.z + o1.z) * inv;
  yv.w = (o0.w + o1.w) * inv;

  float sm = yv.x + yv.y + yv.z + yv.w;
#pragma unroll
  for (int o = 1; o < 64; o <<= 1) sm += __shfl_xor(sm, o, 64);
  if ((t & 63) == 0) red[t >> 6] = sm;
  __syncthreads();
  const float mean = (red[0] + red[1] + red[2] + red[3]) * (1.0f / 1024.0f);
  __syncthreads();

  const float d0 = yv.x - mean, d1 = yv.y - mean, d2 = yv.z - mean, d3 = yv.w - mean;
  float ss = d0 * d0 + d1 * d1 + d2 * d2 + d3 * d3;
#pragma unroll
  for (int o = 1; o < 64; o <<= 1) ss += __shfl_xor(ss, o, 64);
  if ((t & 63) == 0) red[t >> 6] = ss;
  __syncthreads();
  const float var = (red[0] + red[1] + red[2] + red[3]) * (1.0f / 1023.0f);
  const float rstd = 1.0f / (sqrtf(var) + 1e-6f);

  const float4 bv = *(const float4*)(base + off);
  const float4 av = *(const float4*)(alpha + (size_t)t * 4);
  const float4 ev = *(const float4*)(beta + (size_t)t * 4);

  float4 ov;
  ov.x = bv.x + av.x * d0 * rstd + ev.x;
  ov.y = bv.y + av.y * d1 * rstd + ev.y;
  ov.z = bv.z + av.z * d2 * rstd + ev.z;
  ov.w = bv.w + av.w * d3 * rstd + ev.w;
  *(float4*)(outf + off) = ov;
  ushort4 ob;
  ob.x = f2bf(ov.x); ob.y = f2bf(ov.y); ob.z = f2bf(ov.z); ob.w = f2bf(ov.w);
  *(ushort4*)(outb + off) = ob;
}

// Final LN: y = sum of 4 bf16 split-K partials + bias; out fp32.
__global__ __launch_bounds__(256) void ln_res4(
    const float* __restrict__ base, const u16* __restrict__ parts,
    const float* __restrict__ biasv,
    const float* __restrict__ alpha, const float* __restrict__ beta,
    float* __restrict__ outf) {
  __shared__ float red[4];
  const int row = blockIdx.x;
  const int t = threadIdx.x;
  const size_t off = (size_t)row * 1024 + t * 4;
  const size_t stride = (size_t)4096 * 1024;

  float4 yv = *(const float4*)(biasv + (size_t)t * 4);
#pragma unroll
  for (int zi = 0; zi < 4; zi++) {
    const ushort4 pz = *(const ushort4*)(parts + zi * stride + off);
    yv.x += bf2f(pz.x); yv.y += bf2f(pz.y);
    yv.z += bf2f(pz.z); yv.w += bf2f(pz.w);
  }

  float s = yv.x + yv.y + yv.z + yv.w;
#pragma unroll
  for (int o = 1; o < 64; o <<= 1) s += __shfl_xor(s, o, 64);
  if ((t & 63) == 0) red[t >> 6] = s;
  __syncthreads();
  const float mean = (red[0] + red[1] + red[2] + red[3]) * (1.0f / 1024.0f);
  __syncthreads();

  const float d0 = yv.x - mean, d1 = yv.y - mean, d2 = yv.z - mean, d3 = yv.w - mean;
  float ss = d0 * d0 + d1 * d1 + d2 * d2 + d3 * d3;
#pragma unroll
  for (int o = 1; o < 64; o <<= 1) ss += __shfl_xor(ss, o, 64);
  if ((t & 63) == 0) red[t >> 6] = ss;
  __syncthreads();
  const float var = (red[0] + red[1] + red[2] + red[3]) * (1.0f / 1023.0f);
  const float rstd = 1.0f / (sqrtf(var) + 1e-6f);

  const float4 bv = *(const float4*)(base + off);
  const float4 av = *(const float4*)(alpha + (size_t)t * 4);
  const float4 ev = *(const float4*)(beta + (size_t)t * 4);

  float4 ov;
  ov.x = bv.x + av.x * d0 * rstd + ev.x;
  ov.y = bv.y + av.y * d1 * rstd + ev.y;
  ov.z = bv.z + av.z * d2 * rstd + ev.z;
  ov.w = bv.w + av.w * d3 * rstd + ev.w;
  *(float4*)(outf + off) = ov;
}

// ---------------------------------------------------------------------------
extern "C" void kernel_launch(void* const* d_in, const int* in_sizes, int n_in,
                              void* d_out, int out_size, void* d_ws,
                              size_t ws_size, hipStream_t stream) {
  const float* x  = (const float*)d_in[0];
  const int* mask = (const int*)d_in[1];
  const float* Wq = (const float*)d_in[2];
  const float* bq = (const float*)d_in[3];
  const float* Wk = (const float*)d_in[4];
  const float* bk = (const float*)d_in[5];
  const float* Wv = (const float*)d_in[6];
  const float* bv = (const float*)d_in[7];
  const float* W1 = (const float*)d_in[8];
  const float* b1 = (const float*)d_in[9];
  const float* W2 = (const float*)d_in[10];
  const float* b2 = (const float*)d_in[11];
  const float* alpha1 = (const float*)d_in[12];
  const float* beta1  = (const float*)d_in[13];
  const float* alpha2 = (const float*)d_in[14];
  const float* beta2  = (const float*)d_in[15];
  float* out = (float*)d_out;

  // workspace carve-up (bytes), total ~175 MB
  char* p = (char*)d_ws;
  u16* xb      = (u16*)p;  p += (size_t)4096 * 1024 * 2;
  u16* WqkvT   = (u16*)p;  p += (size_t)3072 * 1024 * 2;
  u16* W1T     = (u16*)p;  p += (size_t)4096 * 1024 * 2;
  u16* W2T     = (u16*)p;  p += (size_t)1024 * 4096 * 2;
  u16* Qbuf    = (u16*)p;  p += (size_t)32 * 2048 * 64 * 2;
  u16* Kbuf    = (u16*)p;  p += (size_t)32 * 2048 * 64 * 2;
  u16* Vbuf    = (u16*)p;  p += (size_t)32 * 2048 * 64 * 2;  // V^T [bh][e][s]
  float* attnp = (float*)p; p += (size_t)2 * 4096 * 1024 * 4;  // O partials
  float* lbuf  = (float*)p; p += (size_t)2 * 32 * 2048 * 4;    // l partials
  float* x1f   = (float*)p; p += (size_t)4096 * 1024 * 4;
  u16* x1b     = (u16*)p;  p += (size_t)4096 * 1024 * 2;
  u16* hbuf    = (u16*)p;  p += (size_t)4096 * 4096 * 2;
  u16* ffnp    = (u16*)p;  p += (size_t)4 * 4096 * 1024 * 2;  // 4 bf16 partials

  // 1) merged prep: transposes + x cast
  prep_kernel<<<15360, 256, 0, stream>>>(Wq, Wk, Wv, WqkvT, W1, W1T, W2, W2T,
                                         x, xb);

  // 2) fused QKV projection (V written transposed)
  gemm_bt<0><<<dim3(24, 32), 256, 0, stream>>>(
      xb, 1024, WqkvT, 1024, 4096, 3072, 1024, bq, bk, bv, Qbuf, Kbuf, Vbuf);

  // 3) flash attention, split-S x2 -> unnormalized partials
  attn_kernel<<<dim3(32, 32, 2), 256, 0, stream>>>(Qbuf, Kbuf, Vbuf, mask,
                                                   attnp, lbuf);

  // 4) x1 = x + LN(combine(attn))   (fp32 + bf16 copies)
  ln_attn<<<4096, 256, 0, stream>>>(x, attnp, lbuf, alpha1, beta1, x1f, x1b);

  // 5) h = relu(x1 @ W1 + b1) -> bf16
  gemm_bt<1><<<dim3(32, 32), 256, 0, stream>>>(
      x1b, 1024, W1T, 1024, 4096, 4096, 1024, b1, nullptr, nullptr,
      hbuf, nullptr, nullptr);

  // 6) ffn partials: h @ W2 split-K x4 -> bf16 partials
  gemm_bt<3><<<dim3(8, 32, 4), 256, 0, stream>>>(
      hbuf, 4096, W2T, 4096, 4096, 1024, 1024, nullptr, nullptr, nullptr,
      ffnp, nullptr, nullptr);

  // 7) out = x1 + LN(p0+p1+p2+p3 + b2)
  ln_res4<<<4096, 256, 0, stream>>>(x1f, ffnp, b2, alpha2, beta2, out);
}

// Round 8
// 449.174 us; speedup vs baseline: 1.1419x; 1.0715x over previous
//
#include <hip/hip_runtime.h>

// EncoderBlock on MI355X (gfx950). B=2,S=2048,D=1024,H=16,Dh=64.
// Round 8: XCD-locality grid swizzle (M-tile = blockIdx.x so same-A blocks
// share an XCD L2), FFN2 split-K x2 (r7's x4 was fetch-bound: 161 MB), attn
// partials in bf16.

#define DEV __device__ __forceinline__

typedef unsigned short u16;
typedef __attribute__((ext_vector_type(8))) short bfrag;    // 8 bf16 payload
typedef __attribute__((ext_vector_type(8))) __bf16 bf16x8;  // MFMA operand type
typedef __attribute__((ext_vector_type(4))) float facc;     // MFMA C/D frag

DEV float bf2f(u16 u) {
  unsigned int x = ((unsigned int)u) << 16;
  return __builtin_bit_cast(float, x);
}
DEV u16 f2bf(float f) {
  unsigned int x = __builtin_bit_cast(unsigned int, f);
  x += 0x7fffu + ((x >> 16) & 1u);  // RNE
  return (u16)(x >> 16);
}

DEV void gl2lds16(const u16* g, u16* l) {
  // async global->LDS DMA, 16B/lane; LDS dest = wave-uniform base + lane*16
  auto gp = (const __attribute__((address_space(1))) unsigned int*)(g);
  auto lp = (__attribute__((address_space(3))) unsigned int*)(l);
  __builtin_amdgcn_global_load_lds(gp, lp, 16, 0, 0);
}

DEV facc mfma16(bfrag a, bfrag b, facc c) {
  return __builtin_amdgcn_mfma_f32_16x16x32_bf16(
      __builtin_bit_cast(bf16x8, a), __builtin_bit_cast(bf16x8, b), c, 0, 0, 0);
}

// ---------------------------------------------------------------------------
// Merged prep: qkv transpose (jobs 0..3071), W1T (3072..7167),
// W2T (7168..11263), x cast (11264..15359). All fp32 -> bf16.
// ---------------------------------------------------------------------------
__global__ __launch_bounds__(256) void prep_kernel(
    const float* __restrict__ Wq, const float* __restrict__ Wk,
    const float* __restrict__ Wv, u16* __restrict__ WqkvT,
    const float* __restrict__ W1, u16* __restrict__ W1T,
    const float* __restrict__ W2, u16* __restrict__ W2T,
    const float* __restrict__ x, u16* __restrict__ xb) {
  __shared__ float tile[32][33];
  const int job = blockIdx.x;
  const int tr = threadIdx.x >> 5, tc = threadIdx.x & 31;

  if (job >= 11264) {  // cast x
    const int i = (job - 11264) * 1024 + threadIdx.x * 4;
    const float4 v = *(const float4*)(x + i);
    ushort4 o;
    o.x = f2bf(v.x); o.y = f2bf(v.y); o.z = f2bf(v.z); o.w = f2bf(v.w);
    *(ushort4*)(xb + i) = o;
    return;
  }

  const float* in;
  u16* out;
  int C, R, c0, r0;
  if (job < 3072) {  // qkv: [H][1024][64] -> rows which*1024+h*64+e, cols d
    const int z = job >> 6, rem = job & 63;
    const int which = z >> 4, h = z & 15;
    in = ((which == 0) ? Wq : (which == 1) ? Wk : Wv) + (size_t)h * 1024 * 64;
    out = WqkvT + ((size_t)which * 1024 + h * 64) * 1024;
    C = 64; R = 1024;
    c0 = (rem & 1) * 32; r0 = (rem >> 1) * 32;
  } else if (job < 7168) {  // W1 [1024][4096] -> W1T [4096][1024]
    const int rem = job - 3072;
    in = W1; out = W1T; C = 4096; R = 1024;
    c0 = (rem & 127) * 32; r0 = (rem >> 7) * 32;
  } else {  // W2 [4096][1024] -> W2T [1024][4096]
    const int rem = job - 7168;
    in = W2; out = W2T; C = 1024; R = 4096;
    c0 = (rem & 31) * 32; r0 = (rem >> 5) * 32;
  }
#pragma unroll
  for (int k = 0; k < 4; k++)
    tile[tr + 8 * k][tc] = in[(size_t)(r0 + tr + 8 * k) * C + c0 + tc];
  __syncthreads();
#pragma unroll
  for (int k = 0; k < 4; k++)
    out[(size_t)(c0 + tr + 8 * k) * R + r0 + tc] = f2bf(tile[tc][tr + 8 * k]);
}

// ---------------------------------------------------------------------------
// GEMM C[M][N] = A[M][K] * Bt[N][K]^T, 128x128 tile, BK=32, single-buffer
// m97 structure. GRID: blockIdx.x = M-tile (so all N-tiles of one M-tile map
// to the same XCD under id%8 round-robin -> A-tile L2 reuse), blockIdx.y =
// N-tile, blockIdx.z = K-split.
// MODE 0: QKV scatter +bias -> bf16 (V transposed [bh][e][s], packed stores).
// MODE 1: +bias, ReLU -> bf16.
// MODE 3: split-K partial -> bf16 partial buffer z (out0 + z*M*N).
// ---------------------------------------------------------------------------
template <int MODE>
__global__ __launch_bounds__(256) void gemm_bt(
    const u16* __restrict__ A, int lda, const u16* __restrict__ Bt, int ldb,
    int M, int N, int K,
    const float* __restrict__ bias0, const float* __restrict__ bias1,
    const float* __restrict__ bias2,
    void* __restrict__ out0, void* __restrict__ out1, void* __restrict__ out2) {
  __shared__ __align__(16) u16 As[4 * 128 * 8];  // 8 KB
  __shared__ __align__(16) u16 Bs[4 * 128 * 8];  // 8 KB
  const int tid = threadIdx.x;
  const int lane = tid & 63;
  const int wave = tid >> 6;
  const int laneM = lane & 15, quad = lane >> 4;
  const int m0 = blockIdx.x * 128, n0 = blockIdx.y * 128;  // swizzled
  const int wm = wave & 1, wn = wave >> 1;

  if (MODE == 3) {  // split-K: shift K-origin
    A += (size_t)blockIdx.z * K;
    Bt += (size_t)blockIdx.z * K;
  }

  facc acc[4][4] = {};

  for (int k0 = 0; k0 < K; k0 += 32) {
    __syncthreads();  // previous tile's readers done
#pragma unroll
    for (int t = 0; t < 2; t++) {
      const int c0 = t * 256 + wave * 64;  // wave-uniform chunk base
      const int kc = c0 >> 7, r0 = c0 & 127;
      gl2lds16(A + (size_t)(m0 + r0 + lane) * lda + (k0 + kc * 8),
               As + (size_t)c0 * 8);
      gl2lds16(Bt + (size_t)(n0 + r0 + lane) * ldb + (k0 + kc * 8),
               Bs + (size_t)c0 * 8);
    }
    __syncthreads();  // staging visible

    bfrag af[4], bfv[4];
#pragma unroll
    for (int i = 0; i < 4; i++)
      af[i] = *(const bfrag*)(As + (quad * 128 + wm * 64 + i * 16 + laneM) * 8);
#pragma unroll
    for (int j = 0; j < 4; j++)
      bfv[j] = *(const bfrag*)(Bs + (quad * 128 + wn * 64 + j * 16 + laneM) * 8);
#pragma unroll
    for (int i = 0; i < 4; i++)
#pragma unroll
      for (int j = 0; j < 4; j++)
        acc[i][j] = mfma16(af[i], bfv[j], acc[i][j]);
  }

  // epilogue: C/D layout col=lane&15, row=quad*4+v
#pragma unroll
  for (int i = 0; i < 4; i++) {
#pragma unroll
    for (int j = 0; j < 4; j++) {
      const int col = n0 + wn * 64 + j * 16 + laneM;
      const int row0 = m0 + wm * 64 + i * 16 + quad * 4;
      if (MODE == 0) {
        const int which = col >> 10, c = col & 1023;
        const float* bp = (which == 0) ? bias0 : (which == 1) ? bias1 : bias2;
        u16* op = (u16*)((which == 0) ? out0 : (which == 1) ? out1 : out2);
        const float bb = bp[c];
        const int b = row0 >> 11, s0 = row0 & 2047;
        const int h = c >> 6, e = c & 63;
        if (which == 2) {  // V^T [bh][e][s]: 4 consecutive s -> one 8B store
          ushort4 pk;
          pk.x = f2bf(acc[i][j][0] + bb);
          pk.y = f2bf(acc[i][j][1] + bb);
          pk.z = f2bf(acc[i][j][2] + bb);
          pk.w = f2bf(acc[i][j][3] + bb);
          *(ushort4*)(op + ((size_t)((b * 16 + h) * 64 + e)) * 2048 + s0) = pk;
        } else {
#pragma unroll
          for (int v = 0; v < 4; v++)
            op[((size_t)(b * 16 + h) * 2048 + s0 + v) * 64 + e] =
                f2bf(acc[i][j][v] + bb);
        }
      } else if (MODE == 1) {
        const float bb = bias0[col];
#pragma unroll
        for (int v = 0; v < 4; v++)
          ((u16*)out0)[(size_t)(row0 + v) * N + col] =
              f2bf(fmaxf(acc[i][j][v] + bb, 0.0f));
      } else {  // MODE 3: bf16 partial z
        u16* op = (u16*)out0 + (size_t)blockIdx.z * M * N;
#pragma unroll
        for (int v = 0; v < 4; v++)
          op[(size_t)(row0 + v) * N + col] = f2bf(acc[i][j][v]);
      }
    }
  }
}

// ---------------------------------------------------------------------------
// Flash attention, split-S: GRID blockIdx.x = bh (co-locates all Q-tiles of a
// head on one XCD: shared K/V L2-resident), blockIdx.y = Q-tile, z = S-half.
// Fixed-max softmax (scores bounded): p = 2^(qk*0.125*log2e + maskbias).
// Writes unnormalized bf16 O-half and fp32 l-half; LN kernel combines.
// Q,K bf16 [bh][s][64]; V bf16 TRANSPOSED [bh][e][s].
// ---------------------------------------------------------------------------
__global__ __launch_bounds__(256) void attn_kernel(
    const u16* __restrict__ Qb, const u16* __restrict__ Kb,
    const u16* __restrict__ VTg, const int* __restrict__ mask,
    u16* __restrict__ Opart, float* __restrict__ lbuf) {
  __shared__ __align__(16) u16 KS[8 * 64 * 8];  // 8 KB: Q stage, then K tiles
  __shared__ __align__(16) u16 VS[8 * 64 * 8];  // 8 KB: V^T chunks kc*64+e
  __shared__ __align__(16) u16 PS[64 * 72];     // P (XOR-swizzled cols)
  __shared__ float MB[1024];                    // additive mask bias (half)
  const int tid = threadIdx.x;
  const int lane = tid & 63;
  const int wave = tid >> 6;
  const int laneM = lane & 15, quad = lane >> 4;
  const int bh = blockIdx.x, b = bh >> 4, h = bh & 15;  // swizzled
  const int q0 = blockIdx.y * 64;
  const int z = blockIdx.z;
  const int sbase = z * 1024;
  const u16* Qh = Qb + (size_t)bh * 2048 * 64;
  const u16* Kh = Kb + (size_t)bh * 2048 * 64 + (size_t)sbase * 64;
  const u16* Vh = VTg + (size_t)bh * 64 * 2048 + sbase;
  const float SC = 0.125f * 1.4426950408889634f;  // Dh^-0.5 * log2(e)

  // mask -> additive bias table for this half (once per block)
#pragma unroll
  for (int t = 0; t < 4; t++) {
    const int i = t * 256 + tid;
    MB[i] = mask[b * 2048 + sbase + i] ? 0.0f : -1e30f;
  }

  // stage Q tile (64x64) into KS as chunks c = kc*64 + r
#pragma unroll
  for (int t = 0; t < 2; t++) {
    const int c0 = t * 256 + wave * 64;
    gl2lds16(Qh + (size_t)(q0 + lane) * 64 + (c0 >> 6) * 8, KS + (size_t)c0 * 8);
  }
  __syncthreads();
  bfrag qf[2];
#pragma unroll
  for (int hf = 0; hf < 2; hf++)
    qf[hf] = *(const bfrag*)(KS + ((hf * 4 + quad) * 64 + wave * 16 + laneM) * 8);

  float lsum[4] = {0.0f, 0.0f, 0.0f, 0.0f};
  facc oacc[4] = {};
  const int pq = quad ^ ((laneM >> 2) & 2);  // PS read swizzle

  for (int t0 = 0; t0 < 1024; t0 += 64) {
    __syncthreads();  // all waves done reading KS/VS (qf on iter 0)
#pragma unroll
    for (int t = 0; t < 2; t++) {
      const int c0 = t * 256 + wave * 64;
      gl2lds16(Kh + (size_t)(t0 + lane) * 64 + (c0 >> 6) * 8, KS + (size_t)c0 * 8);
    }
#pragma unroll
    for (int t = 0; t < 2; t++) {
      const int c0 = t * 256 + wave * 64;
      gl2lds16(Vh + (size_t)lane * 2048 + t0 + (c0 >> 6) * 8, VS + (size_t)c0 * 8);
    }
    __syncthreads();

    // S = Q K^T
    facc sacc[4] = {};
#pragma unroll
    for (int j8 = 0; j8 < 4; j8++)
#pragma unroll
      for (int hf = 0; hf < 2; hf++) {
        bfrag kf = *(const bfrag*)(KS + ((hf * 4 + quad) * 64 + j8 * 16 + laneM) * 8);
        sacc[j8] = mfma16(qf[hf], kf, sacc[j8]);
      }

    float mb4[4];
#pragma unroll
    for (int j8 = 0; j8 < 4; j8++) mb4[j8] = MB[t0 + j8 * 16 + laneM];

    // p = 2^(s*SC + bias); per-lane partial sums; write bf16 P (swizzled)
#pragma unroll
    for (int v = 0; v < 4; v++) {
      u16* psrow = PS + (wave * 16 + quad * 4 + v) * 72 + laneM;
#pragma unroll
      for (int j8 = 0; j8 < 4; j8++) {
        const float pv = exp2f(fmaf(sacc[j8][v], SC, mb4[j8]));
        lsum[v] += pv;
        psrow[(j8 ^ (quad >> 1)) * 16] =
            (u16)((__builtin_bit_cast(unsigned int, pv) + 0x8000u) >> 16);
      }
    }

    // O += P @ V  (PS rows wave-private; VS chunk = kc*64 + e)
#pragma unroll
    for (int kc4 = 0; kc4 < 2; kc4++) {
      bfrag pf = *(const bfrag*)(PS + (wave * 16 + laneM) * 72 + kc4 * 32 + pq * 8);
#pragma unroll
      for (int je = 0; je < 4; je++) {
        bfrag vf = *(const bfrag*)(VS + ((kc4 * 4 + quad) * 64 + je * 16 + laneM) * 8);
        oacc[je] = mfma16(pf, vf, oacc[je]);
      }
    }
  }

  // reduce l over the 16-lane row group; write unnormalized bf16 partials
#pragma unroll
  for (int v = 0; v < 4; v++) {
    float l = lsum[v];
    l += __shfl_xor(l, 1, 16);
    l += __shfl_xor(l, 2, 16);
    l += __shfl_xor(l, 4, 16);
    l += __shfl_xor(l, 8, 16);
    const int s = q0 + wave * 16 + quad * 4 + v;
    if (laneM == 0) lbuf[((size_t)(z * 32 + bh)) * 2048 + s] = l;
    u16* dst = Opart + (size_t)z * 4096 * 1024 +
               ((size_t)(b * 2048 + s)) * 1024 + h * 64;
#pragma unroll
    for (int je = 0; je < 4; je++)
      dst[je * 16 + laneM] = f2bf(oacc[je][v]);
  }
}

// ---------------------------------------------------------------------------
// x1 = x + LN((O0+O1)/(l0+l1)); fused attention combine + LayerNorm.
// O partials bf16. Writes fp32 + bf16 copies.
// ---------------------------------------------------------------------------
__global__ __launch_bounds__(256) void ln_attn(
    const float* __restrict__ base, const u16* __restrict__ Opart,
    const float* __restrict__ lbuf,
    const float* __restrict__ alpha, const float* __restrict__ beta,
    float* __restrict__ outf, u16* __restrict__ outb) {
  __shared__ float red[4];
  const int row = blockIdx.x;           // token = b*2048 + s
  const int t = threadIdx.x;
  const int b = row >> 11, s = row & 2047;
  const int h = t >> 4;                 // head of columns t*4..t*4+3
  const size_t off = (size_t)row * 1024 + t * 4;
  const size_t zstride = (size_t)4096 * 1024;

  const float l0 = lbuf[((size_t)(b * 16 + h)) * 2048 + s];
  const float l1 = lbuf[((size_t)(32 + b * 16 + h)) * 2048 + s];
  const float inv = 1.0f / (l0 + l1);

  const ushort4 o0 = *(const ushort4*)(Opart + off);
  const ushort4 o1 = *(const ushort4*)(Opart + zstride + off);
  float4 yv;
  yv.x = (bf2f(o0.x) + bf2f(o1.x)) * inv;
  yv.y = (bf2f(o0.y) + bf2f(o1.y)) * inv;
  yv.z = (bf2f(o0.z) + bf2f(o1.z)) * inv;
  yv.w = (bf2f(o0.w) + bf2f(o1.w)) * inv;

  float sm = yv.x + yv.y + yv.z + yv.w;
#pragma unroll
  for (int o = 1; o < 64; o <<= 1) sm += __shfl_xor(sm, o, 64);
  if ((t & 63) == 0) red[t >> 6] = sm;
  __syncthreads();
  const float mean = (red[0] + red[1] + red[2] + red[3]) * (1.0f / 1024.0f);
  __syncthreads();

  const float d0 = yv.x - mean, d1 = yv.y - mean, d2 = yv.z - mean, d3 = yv.w - mean;
  float ss = d0 * d0 + d1 * d1 + d2 * d2 + d3 * d3;
#pragma unroll
  for (int o = 1; o < 64; o <<= 1) ss += __shfl_xor(ss, o, 64);
  if ((t & 63) == 0) red[t >> 6] = ss;
  __syncthreads();
  const float var = (red[0] + red[1] + red[2] + red[3]) * (1.0f / 1023.0f);
  const float rstd = 1.0f / (sqrtf(var) + 1e-6f);

  const float4 bv = *(const float4*)(base + off);
  const float4 av = *(const float4*)(alpha + (size_t)t * 4);
  const float4 ev = *(const float4*)(beta + (size_t)t * 4);

  float4 ov;
  ov.x = bv.x + av.x * d0 * rstd + ev.x;
  ov.y = bv.y + av.y * d1 * rstd + ev.y;
  ov.z = bv.z + av.z * d2 * rstd + ev.z;
  ov.w = bv.w + av.w * d3 * rstd + ev.w;
  *(float4*)(outf + off) = ov;
  ushort4 ob;
  ob.x = f2bf(ov.x); ob.y = f2bf(ov.y); ob.z = f2bf(ov.z); ob.w = f2bf(ov.w);
  *(ushort4*)(outb + off) = ob;
}

// Final LN: y = sum of 2 bf16 split-K partials + bias; out fp32.
__global__ __launch_bounds__(256) void ln_res2(
    const float* __restrict__ base, const u16* __restrict__ parts,
    const float* __restrict__ biasv,
    const float* __restrict__ alpha, const float* __restrict__ beta,
    float* __restrict__ outf) {
  __shared__ float red[4];
  const int row = blockIdx.x;
  const int t = threadIdx.x;
  const size_t off = (size_t)row * 1024 + t * 4;
  const size_t stride = (size_t)4096 * 1024;

  float4 yv = *(const float4*)(biasv + (size_t)t * 4);
#pragma unroll
  for (int zi = 0; zi < 2; zi++) {
    const ushort4 pz = *(const ushort4*)(parts + zi * stride + off);
    yv.x += bf2f(pz.x); yv.y += bf2f(pz.y);
    yv.z += bf2f(pz.z); yv.w += bf2f(pz.w);
  }

  float s = yv.x + yv.y + yv.z + yv.w;
#pragma unroll
  for (int o = 1; o < 64; o <<= 1) s += __shfl_xor(s, o, 64);
  if ((t & 63) == 0) red[t >> 6] = s;
  __syncthreads();
  const float mean = (red[0] + red[1] + red[2] + red[3]) * (1.0f / 1024.0f);
  __syncthreads();

  const float d0 = yv.x - mean, d1 = yv.y - mean, d2 = yv.z - mean, d3 = yv.w - mean;
  float ss = d0 * d0 + d1 * d1 + d2 * d2 + d3 * d3;
#pragma unroll
  for (int o = 1; o < 64; o <<= 1) ss += __shfl_xor(ss, o, 64);
  if ((t & 63) == 0) red[t >> 6] = ss;
  __syncthreads();
  const float var = (red[0] + red[1] + red[2] + red[3]) * (1.0f / 1023.0f);
  const float rstd = 1.0f / (sqrtf(var) + 1e-6f);

  const float4 bv = *(const float4*)(base + off);
  const float4 av = *(const float4*)(alpha + (size_t)t * 4);
  const float4 ev = *(const float4*)(beta + (size_t)t * 4);

  float4 ov;
  ov.x = bv.x + av.x * d0 * rstd + ev.x;
  ov.y = bv.y + av.y * d1 * rstd + ev.y;
  ov.z = bv.z + av.z * d2 * rstd + ev.z;
  ov.w = bv.w + av.w * d3 * rstd + ev.w;
  *(float4*)(outf + off) = ov;
}

// ---------------------------------------------------------------------------
extern "C" void kernel_launch(void* const* d_in, const int* in_sizes, int n_in,
                              void* d_out, int out_size, void* d_ws,
                              size_t ws_size, hipStream_t stream) {
  const float* x  = (const float*)d_in[0];
  const int* mask = (const int*)d_in[1];
  const float* Wq = (const float*)d_in[2];
  const float* bq = (const float*)d_in[3];
  const float* Wk = (const float*)d_in[4];
  const float* bk = (const float*)d_in[5];
  const float* Wv = (const float*)d_in[6];
  const float* bv = (const float*)d_in[7];
  const float* W1 = (const float*)d_in[8];
  const float* b1 = (const float*)d_in[9];
  const float* W2 = (const float*)d_in[10];
  const float* b2 = (const float*)d_in[11];
  const float* alpha1 = (const float*)d_in[12];
  const float* beta1  = (const float*)d_in[13];
  const float* alpha2 = (const float*)d_in[14];
  const float* beta2  = (const float*)d_in[15];
  float* out = (float*)d_out;

  // workspace carve-up (bytes), total ~135 MB
  char* p = (char*)d_ws;
  u16* xb      = (u16*)p;  p += (size_t)4096 * 1024 * 2;
  u16* WqkvT   = (u16*)p;  p += (size_t)3072 * 1024 * 2;
  u16* W1T     = (u16*)p;  p += (size_t)4096 * 1024 * 2;
  u16* W2T     = (u16*)p;  p += (size_t)1024 * 4096 * 2;
  u16* Qbuf    = (u16*)p;  p += (size_t)32 * 2048 * 64 * 2;
  u16* Kbuf    = (u16*)p;  p += (size_t)32 * 2048 * 64 * 2;
  u16* Vbuf    = (u16*)p;  p += (size_t)32 * 2048 * 64 * 2;  // V^T [bh][e][s]
  u16* attnp   = (u16*)p;  p += (size_t)2 * 4096 * 1024 * 2;  // bf16 O partials
  float* lbuf  = (float*)p; p += (size_t)2 * 32 * 2048 * 4;   // l partials
  float* x1f   = (float*)p; p += (size_t)4096 * 1024 * 4;
  u16* x1b     = (u16*)p;  p += (size_t)4096 * 1024 * 2;
  u16* hbuf    = (u16*)p;  p += (size_t)4096 * 4096 * 2;
  u16* ffnp    = (u16*)p;  p += (size_t)2 * 4096 * 1024 * 2;  // 2 bf16 partials

  // 1) merged prep: transposes + x cast
  prep_kernel<<<15360, 256, 0, stream>>>(Wq, Wk, Wv, WqkvT, W1, W1T, W2, W2T,
                                         x, xb);

  // 2) fused QKV projection (V written transposed); x = M-tile
  gemm_bt<0><<<dim3(32, 24), 256, 0, stream>>>(
      xb, 1024, WqkvT, 1024, 4096, 3072, 1024, bq, bk, bv, Qbuf, Kbuf, Vbuf);

  // 3) flash attention, split-S x2 -> unnormalized partials; x = bh
  attn_kernel<<<dim3(32, 32, 2), 256, 0, stream>>>(Qbuf, Kbuf, Vbuf, mask,
                                                   attnp, lbuf);

  // 4) x1 = x + LN(combine(attn))   (fp32 + bf16 copies)
  ln_attn<<<4096, 256, 0, stream>>>(x, attnp, lbuf, alpha1, beta1, x1f, x1b);

  // 5) h = relu(x1 @ W1 + b1) -> bf16; x = M-tile
  gemm_bt<1><<<dim3(32, 32), 256, 0, stream>>>(
      x1b, 1024, W1T, 1024, 4096, 4096, 1024, b1, nullptr, nullptr,
      hbuf, nullptr, nullptr);

  // 6) ffn partials: h @ W2 split-K x2 -> bf16 partials; x = M-tile
  gemm_bt<3><<<dim3(32, 8, 2), 256, 0, stream>>>(
      hbuf, 4096, W2T, 4096, 4096, 1024, 2048, nullptr, nullptr, nullptr,
      ffnp, nullptr, nullptr);

  // 7) out = x1 + LN(p0+p1 + b2)
  ln_res2<<<4096, 256, 0, stream>>>(x1f, ffnp, b2, alpha2, beta2, out);
}